// Round 11
// baseline (197.695 us; speedup 1.0000x reference)
//
#include <hip/hip_runtime.h>
#include <hip/hip_cooperative_groups.h>

namespace cg = cooperative_groups;

#define HIDN 512
#define NHEAD 8
#define DHEAD 64
#define NB 4
#define NL 256
#define NROW 1024   // NB*NL

#define SCALE2 2.8853900817779268f   // 2*log2(e)
#define LOG2E  1.4426950408889634f
#define NEG2LOG2E -2.8853900817779268f

// workspace layout (float offsets)
#define WS_WQB 0
#define WS_WKB (WS_WQB + 131072)
#define WS_BQF (WS_WKB + 131072)
#define WS_BKF (WS_BQF + 512)
#define WS_QBF (WS_BKF + 512)          // query bf16; reused as X bf16 after proj
#define WS_KBF (WS_QBF + 262144)
#define WS_VBF (WS_KBF + 262144)
#define WS_WVB (WS_VBF + 262144)
#define WS_WOB (WS_WVB + 131072)
#define WS_EQ  (WS_WOB + 131072)
#define WS_EK  (WS_EQ + 524288)
#define WS_VF  (WS_EK + 524288)

typedef __attribute__((ext_vector_type(4))) float f32x4;
typedef __attribute__((ext_vector_type(8))) short bf16x8;

__device__ __forceinline__ short f2bf(float x) {
  unsigned u = __float_as_uint(x);
  u += 0x7fffu + ((u >> 16) & 1u);   // RNE
  return (short)(u >> 16);
}

// One cooperative kernel, 4 phases separated by grid.sync():
//   A: f32->bf16 conversions (1 chunk/thread) + W1/W2 fold into Wq/Wk (bid<64)
//   B: MFMA projections -> EQ=exp2(Qt'), EK=exp2(Kt'), VF (bf16 B-fragments)
//   C: attn (paired-rcp energy, no-max softmax, MFMA PV) -- 2 passes
//   D: MFMA output GEMM
__global__ __launch_bounds__(1024, 4) void fused_all(
    const float* __restrict__ q, const float* __restrict__ kin, const float* __restrict__ v,
    const float* __restrict__ Wq, const float* __restrict__ bq,
    const float* __restrict__ Wk, const float* __restrict__ bk,
    const float* __restrict__ Wv, const float* __restrict__ bv,
    const float* __restrict__ W1, const float* __restrict__ b1,
    const float* __restrict__ W2, const float* __restrict__ b2,
    const float* __restrict__ va_w, const float* __restrict__ Wo,
    const float* __restrict__ bo,
    float* __restrict__ ws, float* __restrict__ out)
{
  cg::grid_group grid = cg::this_grid();
  const int bid = blockIdx.x;
  const int tid = threadIdx.x;
  const int sub = tid >> 8;       // 4 sub-blocks of 256 threads
  const int lt  = tid & 255;

  __shared__ __align__(16) float WtlS[4][16][68];   // 17.4 KB (phase A fold)
  __shared__ __align__(16) short aLb[8][64][8];     // 8 KB    (phase C)
  __shared__ __align__(16) float reds[4][4][4];     //          (phase C)

  float* attn_out = out + NROW*HIDN;

  // ---------------- Phase A ----------------
  {
    const int ci = bid * 1024 + tid;     // 0..262143, exactly one 8-elem chunk each
    const int i = ci * 8;
    const float* src; short* dst; int rel;
    if (i < 524288)        { src = q;   dst = (short*)(ws + WS_QBF); rel = i; }
    else if (i < 1048576)  { src = kin; dst = (short*)(ws + WS_KBF); rel = i - 524288; }
    else if (i < 1572864)  { src = v;   dst = (short*)(ws + WS_VBF); rel = i - 1048576; }
    else if (i < 1835008)  { src = Wv;  dst = (short*)(ws + WS_WVB); rel = i - 1572864; }
    else                   { src = Wo;  dst = (short*)(ws + WS_WOB); rel = i - 1835008; }
    const float4 a = *reinterpret_cast<const float4*>(src + rel);
    const float4 b = *reinterpret_cast<const float4*>(src + rel + 4);
    bf16x8 o;
    o[0] = f2bf(a.x); o[1] = f2bf(a.y); o[2] = f2bf(a.z); o[3] = f2bf(a.w);
    o[4] = f2bf(b.x); o[5] = f2bf(b.y); o[6] = f2bf(b.z); o[7] = f2bf(b.w);
    *reinterpret_cast<bf16x8*>(dst + rel) = o;
  }
  if (bid < 64) {
    // weight fold: virtual block vb = bid*4+sub in [0,256)
    const int vb = bid*4 + sub;
    const int which = vb >> 7;
    const int y  = (vb >> 2) & 31;
    const int h  = y >> 2;
    const int ig = y & 3;
    const int c0 = (vb & 3) * 128;
    const float* Wsrc = which ? Wk : Wq;
    const float* bsrc = which ? bk : bq;
    const float* Wt   = which ? W2 : W1;
    const float* bt   = which ? b2 : b1;
    short* Wout = (short*)(ws + (which ? WS_WKB : WS_WQB));
    float* bout = ws + (which ? WS_BKF : WS_BQF);
    float (*Wtl)[68] = WtlS[sub];

    for (int t = lt; t < 16*64; t += 256)
      Wtl[t >> 6][t & 63] = Wt[(ig*16 + (t >> 6))*64 + (t & 63)];
    __syncthreads();

    const int c  = c0 + (lt & 127);
    const int i0 = (lt >> 7) * 8;
    float acc[8];
#pragma unroll
    for (int ii = 0; ii < 8; ++ii) acc[ii] = 0.f;
    for (int j0 = 0; j0 < 64; j0 += 4) {
      const float s0 = Wsrc[(h*64 + j0 + 0)*HIDN + c];
      const float s1 = Wsrc[(h*64 + j0 + 1)*HIDN + c];
      const float s2 = Wsrc[(h*64 + j0 + 2)*HIDN + c];
      const float s3 = Wsrc[(h*64 + j0 + 3)*HIDN + c];
#pragma unroll
      for (int ii = 0; ii < 8; ++ii) {
        const float4 wv4 = *reinterpret_cast<const float4*>(&Wtl[i0+ii][j0]);
        float a = acc[ii];
        a = fmaf(wv4.x, s0, a);
        a = fmaf(wv4.y, s1, a);
        a = fmaf(wv4.z, s2, a);
        a = fmaf(wv4.w, s3, a);
        acc[ii] = a;
      }
    }
#pragma unroll
    for (int ii = 0; ii < 8; ++ii)
      Wout[(h*64 + ig*16 + i0 + ii)*HIDN + c] = f2bf(acc[ii] * SCALE2);

    if ((vb & 3) == 0 && lt < 16) {
      const int il = lt;
      float a = bt[ig*16 + il];
      for (int j = 0; j < 64; ++j)
        a = fmaf(Wtl[il][j], bsrc[h*64 + j], a);
      bout[h*64 + ig*16 + il] = a * SCALE2;
    }
  }
  grid.sync();

  // ---------------- Phase B: projections ----------------
  {
    const int vb = bid*4 + sub;          // 0..1023, use 768
    if (vb < 768) {
      const int z  = vb >> 8;
      const int r  = vb & 255;
      const int bx = r & 15;
      const int by = r >> 4;
      const short* A; const short* W; const float* bias;
      if (z == 0)      { A = (const short*)(ws + WS_QBF); W = (const short*)(ws + WS_WQB); bias = ws + WS_BQF; }
      else if (z == 1) { A = (const short*)(ws + WS_KBF); W = (const short*)(ws + WS_WKB); bias = ws + WS_BKF; }
      else             { A = (const short*)(ws + WS_VBF); W = (const short*)(ws + WS_WVB); bias = bv; }

      const int wid  = lt >> 6;
      const int lane = lt & 63;
      const int mt = by*4 + wid;
      const int nb = bx*32;
      const short* aptr = A + (mt*16 + (lane & 15))*HIDN + (lane >> 4)*8;
      const short* wptr = W + (nb + (lane & 15))*HIDN + (lane >> 4)*8;

      f32x4 acc[2] = {{0,0,0,0},{0,0,0,0}};
#pragma unroll 4
      for (int k0 = 0; k0 < HIDN; k0 += 32) {
        const bf16x8 af = *reinterpret_cast<const bf16x8*>(aptr + k0);
        const short* wp = wptr + k0;
#pragma unroll
        for (int t = 0; t < 2; ++t)
          acc[t] = __builtin_amdgcn_mfma_f32_16x16x32_bf16(
              af, *reinterpret_cast<const bf16x8*>(wp + t*16*HIDN), acc[t], 0, 0, 0);
      }

      const int rbase = mt*16 + (lane >> 4)*4;
      if (z < 2) {
        float* dst = ws + (z == 0 ? WS_EQ : WS_EK);
#pragma unroll
        for (int t = 0; t < 2; ++t) {
          const int c = nb + t*16 + (lane & 15);
          const float bc = bias[c];
          const int hh = c >> 6, d = c & 63;
#pragma unroll
          for (int r2 = 0; r2 < 4; ++r2) {
            const int R = rbase + r2;
            dst[(((R >> 8)*NHEAD + hh)*NL + (R & 255))*DHEAD + d] =
                __builtin_amdgcn_exp2f(acc[t][r2] + bc);
          }
        }
      } else {
        short* vf = (short*)(ws + WS_VF);
#pragma unroll
        for (int t = 0; t < 2; ++t) {
          const int c = nb + t*16 + (lane & 15);
          const float bc = bias[c];
          const int hh = c >> 6, d = c & 63;
#pragma unroll
          for (int r2 = 0; r2 < 4; ++r2) {
            const int R = rbase + r2;
            const int l = R & 255;
            const int bh = (R >> 8)*NHEAD + hh;
            const int tile = ((l >> 5) << 2) + (d >> 4);
            const int lanep = (((l >> 3) & 3) << 4) + (d & 15);
            vf[((bh*32 + tile)*64 + lanep)*8 + (l & 7)] = f2bf(acc[t][r2] + bc);
          }
        }
      }
    }
  }
  grid.sync();

  // ---------------- Phase C: attention (2 passes of 256 virtual blocks) ----------------
  {
    short* xb = (short*)(ws + WS_QBF);
    for (int pass = 0; pass < 2; ++pass) {
      const int vb = bid + pass*256;
      const int qt = vb & 15;
      const int bh = vb >> 4;
      const float* EKB = ws + WS_EK + bh*NL*DHEAD;
      const short* VF  = (const short*)(ws + WS_VF) + bh*32*64*8;

      const int g  = tid >> 8;
      const int lk = tid & 255;
      const int wv = lk >> 6;
      const int l  = lk & 63;
      const float* EkRow = EKB + lk*DHEAD;
      const int g_u = __builtin_amdgcn_readfirstlane(g);
      const float* EqG = ws + WS_EQ + (bh*NL + qt*16 + g_u*4)*DHEAD;

      float acc[4];
#pragma unroll
      for (int qi = 0; qi < 4; ++qi) acc[qi] = 0.f;

#pragma unroll 1
      for (int d0 = 0; d0 < 64; d0 += 8) {
        const f32x4 ea = *reinterpret_cast<const f32x4*>(EkRow + d0);
        const f32x4 eb = *reinterpret_cast<const f32x4*>(EkRow + d0 + 4);
        const f32x4 vaA = *reinterpret_cast<const f32x4*>(va_w + d0);
        const f32x4 vaB = *reinterpret_cast<const f32x4*>(va_w + d0 + 4);
#pragma unroll
        for (int qi = 0; qi < 4; ++qi) {
          const f32x4 qa = *reinterpret_cast<const f32x4*>(EqG + qi*DHEAD + d0);
          const f32x4 qb = *reinterpret_cast<const f32x4*>(EqG + qi*DHEAD + d0 + 4);
          const float t0 = fmaf(qa.x, ea.x, 1.0f);
          const float t1 = fmaf(qa.y, ea.y, 1.0f);
          const float t2 = fmaf(qa.z, ea.z, 1.0f);
          const float t3 = fmaf(qa.w, ea.w, 1.0f);
          const float t4 = fmaf(qb.x, eb.x, 1.0f);
          const float t5 = fmaf(qb.y, eb.y, 1.0f);
          const float t6 = fmaf(qb.z, eb.z, 1.0f);
          const float t7 = fmaf(qb.w, eb.w, 1.0f);
          float a = acc[qi];
          a = fmaf(fmaf(vaA.x, t1, vaA.y * t0), __builtin_amdgcn_rcpf(t0 * t1), a);
          a = fmaf(fmaf(vaA.z, t3, vaA.w * t2), __builtin_amdgcn_rcpf(t2 * t3), a);
          a = fmaf(fmaf(vaB.x, t5, vaB.y * t4), __builtin_amdgcn_rcpf(t4 * t5), a);
          a = fmaf(fmaf(vaB.z, t7, vaB.w * t6), __builtin_amdgcn_rcpf(t6 * t7), a);
          acc[qi] = a;
        }
      }

      float p[4];
#pragma unroll
      for (int qi = 0; qi < 4; ++qi)
        p[qi] = __builtin_amdgcn_exp2f(acc[qi] * NEG2LOG2E);

#pragma unroll
      for (int qi = 0; qi < 4; ++qi) {
        float s = p[qi];
#pragma unroll
        for (int off = 1; off < 64; off <<= 1)
          s += __shfl_xor(s, off);
        if (l == 0) reds[g][wv][qi] = s;
      }
      {
        const int kb2 = lk >> 5;
        const int lbase = ((lk >> 3) & 3) * 16;
        const int jb = lk & 7;
#pragma unroll
        for (int qi = 0; qi < 4; ++qi)
          aLb[kb2][lbase + g*4 + qi][jb] = f2bf(p[qi]);
      }
      __syncthreads();

      {
        f32x4 s4 = {0.f,0.f,0.f,0.f};
#pragma unroll
        for (int w2 = 0; w2 < 4; ++w2)
          s4 += *reinterpret_cast<const f32x4*>(&reds[g][w2][0]);
        float inv[4];
        inv[0] = __builtin_amdgcn_rcpf(s4.x); inv[1] = __builtin_amdgcn_rcpf(s4.y);
        inv[2] = __builtin_amdgcn_rcpf(s4.z); inv[3] = __builtin_amdgcn_rcpf(s4.w);
#pragma unroll
        for (int qi = 0; qi < 4; ++qi)
          attn_out[(bh*NL + qt*16 + g*4 + qi)*NL + lk] = p[qi] * inv[qi];

        const int wid = tid >> 6;
        if (wid < 4) {
          f32x4 pacc = {0.f,0.f,0.f,0.f};
#pragma unroll
          for (int kb2 = 0; kb2 < 8; ++kb2) {
            const bf16x8 af  = *reinterpret_cast<const bf16x8*>(&aLb[kb2][l][0]);
            const bf16x8 bff = *reinterpret_cast<const bf16x8*>(&VF[((kb2*4 + wid)*64 + l)*8]);
            pacc = __builtin_amdgcn_mfma_f32_16x16x32_bf16(af, bff, pacc, 0, 0, 0);
          }
          const int b_ = bh >> 3, hh = bh & 7;
          const int colv = hh*DHEAD + wid*16 + (l & 15);
#pragma unroll
          for (int r2 = 0; r2 < 4; ++r2) {
            const int row = (l >> 4)*4 + r2;
            const float stot = reds[row>>2][0][row&3] + reds[row>>2][1][row&3]
                             + reds[row>>2][2][row&3] + reds[row>>2][3][row&3];
            xb[(b_*NL + qt*16 + row)*HIDN + colv] = f2bf(pacc[r2] * __builtin_amdgcn_rcpf(stot));
          }
        }
      }
      __syncthreads();   // aLb/reds reuse across passes
    }
  }
  grid.sync();

  // ---------------- Phase D: output GEMM ----------------
  {
    const int vb = bid*4 + sub;
    if (vb < 256) {
      const int bx = vb & 15;
      const int by = vb >> 4;
      const short* A = (const short*)(ws + WS_QBF);
      const short* W = (const short*)(ws + WS_WOB);
      const int wid  = lt >> 6;
      const int lane = lt & 63;
      const int mt = by*4 + wid;
      const int nb = bx*32;
      const short* aptr = A + (mt*16 + (lane & 15))*HIDN + (lane >> 4)*8;
      const short* wptr = W + (nb + (lane & 15))*HIDN + (lane >> 4)*8;

      f32x4 acc[2] = {{0,0,0,0},{0,0,0,0}};
#pragma unroll 4
      for (int k0 = 0; k0 < HIDN; k0 += 32) {
        const bf16x8 af = *reinterpret_cast<const bf16x8*>(aptr + k0);
        const short* wp = wptr + k0;
#pragma unroll
        for (int t = 0; t < 2; ++t)
          acc[t] = __builtin_amdgcn_mfma_f32_16x16x32_bf16(
              af, *reinterpret_cast<const bf16x8*>(wp + t*16*HIDN), acc[t], 0, 0, 0);
      }

      const int rbase = mt*16 + (lane >> 4)*4;
#pragma unroll
      for (int t = 0; t < 2; ++t) {
        const int c = nb + t*16 + (lane & 15);
        const float bc = bo[c];
#pragma unroll
        for (int r2 = 0; r2 < 4; ++r2)
          out[(rbase + r2)*HIDN + c] = acc[t][r2] + bc;
      }
    }
  }
}

extern "C" void kernel_launch(void* const* d_in, const int* in_sizes, int n_in,
                              void* d_out, int out_size, void* d_ws, size_t ws_size,
                              hipStream_t stream) {
  const float* q    = (const float*)d_in[0];
  const float* kin  = (const float*)d_in[1];
  const float* v    = (const float*)d_in[2];
  const float* Wq   = (const float*)d_in[3];
  const float* bq   = (const float*)d_in[4];
  const float* Wk   = (const float*)d_in[5];
  const float* bk   = (const float*)d_in[6];
  const float* Wv   = (const float*)d_in[7];
  const float* bv   = (const float*)d_in[8];
  const float* W1   = (const float*)d_in[9];
  const float* b1   = (const float*)d_in[10];
  const float* W2   = (const float*)d_in[11];
  const float* b2   = (const float*)d_in[12];
  const float* va_w = (const float*)d_in[13];
  const float* Wo   = (const float*)d_in[15];
  const float* bo   = (const float*)d_in[16];

  float* out = (float*)d_out;
  float* ws  = (float*)d_ws;

  void* args[] = {
    (void*)&q, (void*)&kin, (void*)&v,
    (void*)&Wq, (void*)&bq, (void*)&Wk, (void*)&bk, (void*)&Wv, (void*)&bv,
    (void*)&W1, (void*)&b1, (void*)&W2, (void*)&b2,
    (void*)&va_w, (void*)&Wo, (void*)&bo,
    (void*)&ws, (void*)&out
  };
  hipLaunchCooperativeKernel((const void*)fused_all, dim3(256), dim3(1024),
                             args, 0, stream);
}

// Round 12
// 83.234 us; speedup vs baseline: 2.3752x; 2.3752x over previous
//
#include <hip/hip_runtime.h>

#define HIDN 512
#define NHEAD 8
#define DHEAD 64
#define NB 4
#define NL 256
#define NROW 1024   // NB*NL

#define SCALE2 2.8853900817779268f   // 2*log2(e):  exp2(SCALE2*y) = e^{2y}
#define NEG2LOG2E -2.8853900817779268f

// workspace layout (float offsets)
#define WS_EQ  0                       // EQ = e^{2Qt} f32 head-major [32bh][256][64]
#define WS_EK  (WS_EQ + 524288)        // EK = e^{2Kt} f32 head-major
#define WS_VF  (WS_EK + 524288)        // V bf16 MFMA B-fragments [32bh][32tile][64lane][8j]
#define WS_X   (WS_VF + 262144)        // X bf16 [1024][512]

typedef __attribute__((ext_vector_type(4))) float f32x4;
typedef __attribute__((ext_vector_type(8))) short bf16x8;

__device__ __forceinline__ short f2bf(float x) {
  unsigned u = __float_as_uint(x);
  u += 0x7fffu + ((u >> 16) & 1u);   // RNE
  return (short)(u >> 16);
}

__device__ __forceinline__ bf16x8 cvt8(const float* __restrict__ p) {
  const float4 a = *reinterpret_cast<const float4*>(p);
  const float4 b = *reinterpret_cast<const float4*>(p + 4);
  bf16x8 o;
  o[0] = f2bf(a.x); o[1] = f2bf(a.y); o[2] = f2bf(a.z); o[3] = f2bf(a.w);
  o[4] = f2bf(b.x); o[5] = f2bf(b.y); o[6] = f2bf(b.z); o[7] = f2bf(b.w);
  return o;
}

// ---------------- proj2: two-step head projection straight from f32 inputs ----------
// grid (64 mt, 8 h, 3 z), 256 threads (4 waves; wave w = 16-col n-tile of the head).
// stage1: P(16x64) = A_rows @ Wsrc_head^T + bsrc   (K=512, 16 MFMA/wave, f32->bf16 in-reg)
// stage2 (z<2): Qt(16x64) = P @ Wt^T + bt; EQ/EK = exp2(SCALE2*Qt)  (K=64, 2 MFMA/wave)
// z=2: stage1 result IS V_head tile -> write bf16 B-fragments (VF) directly.
__global__ __launch_bounds__(256) void proj2(
    const float* __restrict__ q, const float* __restrict__ kin, const float* __restrict__ v,
    const float* __restrict__ Wq, const float* __restrict__ bq,
    const float* __restrict__ Wk, const float* __restrict__ bk,
    const float* __restrict__ Wv, const float* __restrict__ bv,
    const float* __restrict__ W1, const float* __restrict__ b1,
    const float* __restrict__ W2, const float* __restrict__ b2,
    float* __restrict__ ws)
{
  const int mt = blockIdx.x;          // 16-row m-tile, 0..63
  const int h  = blockIdx.y;          // head
  const int z  = blockIdx.z;          // 0=Q, 1=K, 2=V
  const int w  = threadIdx.x >> 6;    // wave -> n-tile
  const int l  = threadIdx.x & 63;

  const float* A  = (z == 0) ? q  : (z == 1) ? kin : v;
  const float* Ws = (z == 0) ? Wq : (z == 1) ? Wk  : Wv;
  const float* bs = (z == 0) ? bq : (z == 1) ? bk  : bv;

  __shared__ __align__(16) short Pl[16][72];   // 2.3 KB stage-1 tile (bf16)

  const int colh = w*16 + (l & 15);            // head-local output col 0..63
  const float* aptr = A  + (mt*16 + (l & 15))*HIDN + (l >> 4)*8;
  const float* wptr = Ws + (h*64 + colh)*HIDN + (l >> 4)*8;

  f32x4 acc = {0.f, 0.f, 0.f, 0.f};
#pragma unroll 4
  for (int k0 = 0; k0 < HIDN; k0 += 32) {
    const bf16x8 af = cvt8(aptr + k0);
    const bf16x8 bf = cvt8(wptr + k0);
    acc = __builtin_amdgcn_mfma_f32_16x16x32_bf16(af, bf, acc, 0, 0, 0);
  }
  const float bc = bs[h*64 + colh];

  if (z == 2) {
    short* vf = reinterpret_cast<short*>(ws + WS_VF);
#pragma unroll
    for (int r = 0; r < 4; ++r) {
      const int R = mt*16 + (l >> 4)*4 + r;    // global row
      const int l2 = R & 255;                  // key index
      const int bh = (R >> 8)*NHEAD + h;
      const int tile = ((l2 >> 5) << 2) + (colh >> 4);
      const int lanep = (((l2 >> 3) & 3) << 4) + (colh & 15);
      vf[((bh*32 + tile)*64 + lanep)*8 + (l2 & 7)] = f2bf(acc[r] + bc);
    }
  } else {
    // publish P (with stage-1 bias) to LDS
#pragma unroll
    for (int r = 0; r < 4; ++r)
      Pl[(l >> 4)*4 + r][colh] = f2bf(acc[r] + bc);
    __syncthreads();

    const float* Wt = (z == 0) ? W1 : W2;
    const float* bt = (z == 0) ? b1 : b2;
    const short* pp  = &Pl[l & 15][(l >> 4)*8];
    const float* wtp = Wt + colh*64 + (l >> 4)*8;

    f32x4 acc2 = {0.f, 0.f, 0.f, 0.f};
#pragma unroll
    for (int j0 = 0; j0 < 64; j0 += 32) {
      const bf16x8 af = *reinterpret_cast<const bf16x8*>(pp + j0);
      const bf16x8 bf = cvt8(wtp + j0);
      acc2 = __builtin_amdgcn_mfma_f32_16x16x32_bf16(af, bf, acc2, 0, 0, 0);
    }
    const float btc = bt[colh];
    float* dst = ws + (z == 0 ? WS_EQ : WS_EK);
#pragma unroll
    for (int r = 0; r < 4; ++r) {
      const int R = mt*16 + (l >> 4)*4 + r;
      const int bh = (R >> 8)*NHEAD + h;
      dst[(bh*NL + (R & 255))*DHEAD + colh] =
          __builtin_amdgcn_exp2f(SCALE2 * (acc2[r] + btc));
    }
  }
}

// ---------------- attn: paired-rcp energy (SGPR Eq/va), no-max softmax, MFMA PV ------
// grid (16 qt, 32 bh), 1024 threads. Identical to r10 (the 59.7us baseline).
__global__ __launch_bounds__(1024, 8) void attn_kernel(
    const float* __restrict__ eqB, const float* __restrict__ ekB,
    const short* __restrict__ vfB, const float* __restrict__ va_w,
    float* __restrict__ attn_out, short* __restrict__ xb)
{
  const int qt = blockIdx.x;
  const int bh = blockIdx.y;
  const int tid = threadIdx.x;

  __shared__ __align__(16) short aLb[8][64][8];      // P as bf16 A-fragments
  __shared__ __align__(16) float reds[4][4][4];      // [qgroup][wave][qi]

  const float* EKB = ekB + bh*NL*DHEAD;
  const short* VF  = vfB + bh*32*64*8;

  const int g  = tid >> 8;        // q-group: rows g*4 .. g*4+3 (wave-uniform)
  const int lk = tid & 255;
  const int wv = lk >> 6;
  const int l  = lk & 63;
  const float* EkRow = EKB + lk*DHEAD;
  const int g_u = __builtin_amdgcn_readfirstlane(g);
  const float* EqG = eqB + (bh*NL + qt*16 + g_u*4)*DHEAD;

  float acc[4];
#pragma unroll
  for (int qi = 0; qi < 4; ++qi) acc[qi] = 0.f;

#pragma unroll 1
  for (int d0 = 0; d0 < 64; d0 += 8) {
    const f32x4 ea = *reinterpret_cast<const f32x4*>(EkRow + d0);
    const f32x4 eb = *reinterpret_cast<const f32x4*>(EkRow + d0 + 4);
    const f32x4 vaA = *reinterpret_cast<const f32x4*>(va_w + d0);       // uniform -> SGPR
    const f32x4 vaB = *reinterpret_cast<const f32x4*>(va_w + d0 + 4);
#pragma unroll
    for (int qi = 0; qi < 4; ++qi) {
      const f32x4 qa = *reinterpret_cast<const f32x4*>(EqG + qi*DHEAD + d0);      // uniform
      const f32x4 qb = *reinterpret_cast<const f32x4*>(EqG + qi*DHEAD + d0 + 4);  // uniform
      const float t0 = fmaf(qa.x, ea.x, 1.0f);
      const float t1 = fmaf(qa.y, ea.y, 1.0f);
      const float t2 = fmaf(qa.z, ea.z, 1.0f);
      const float t3 = fmaf(qa.w, ea.w, 1.0f);
      const float t4 = fmaf(qb.x, eb.x, 1.0f);
      const float t5 = fmaf(qb.y, eb.y, 1.0f);
      const float t6 = fmaf(qb.z, eb.z, 1.0f);
      const float t7 = fmaf(qb.w, eb.w, 1.0f);
      float a = acc[qi];
      a = fmaf(fmaf(vaA.x, t1, vaA.y * t0), __builtin_amdgcn_rcpf(t0 * t1), a);
      a = fmaf(fmaf(vaA.z, t3, vaA.w * t2), __builtin_amdgcn_rcpf(t2 * t3), a);
      a = fmaf(fmaf(vaB.x, t5, vaB.y * t4), __builtin_amdgcn_rcpf(t4 * t5), a);
      a = fmaf(fmaf(vaB.z, t7, vaB.w * t6), __builtin_amdgcn_rcpf(t6 * t7), a);
      acc[qi] = a;
    }
  }

  float p[4];
#pragma unroll
  for (int qi = 0; qi < 4; ++qi)
    p[qi] = __builtin_amdgcn_exp2f(acc[qi] * NEG2LOG2E);

#pragma unroll
  for (int qi = 0; qi < 4; ++qi) {
    float s = p[qi];
#pragma unroll
    for (int off = 1; off < 64; off <<= 1)
      s += __shfl_xor(s, off);
    if (l == 0) reds[g][wv][qi] = s;
  }
  {
    const int kb2 = lk >> 5;
    const int lbase = ((lk >> 3) & 3) * 16;
    const int jb = lk & 7;
#pragma unroll
    for (int qi = 0; qi < 4; ++qi)
      aLb[kb2][lbase + g*4 + qi][jb] = f2bf(p[qi]);
  }
  __syncthreads();

  {
    f32x4 s4 = {0.f,0.f,0.f,0.f};
#pragma unroll
    for (int w2 = 0; w2 < 4; ++w2)
      s4 += *reinterpret_cast<const f32x4*>(&reds[g][w2][0]);
    float inv[4];
    inv[0] = __builtin_amdgcn_rcpf(s4.x); inv[1] = __builtin_amdgcn_rcpf(s4.y);
    inv[2] = __builtin_amdgcn_rcpf(s4.z); inv[3] = __builtin_amdgcn_rcpf(s4.w);
#pragma unroll
    for (int qi = 0; qi < 4; ++qi)
      attn_out[(bh*NL + qt*16 + g*4 + qi)*NL + lk] = p[qi] * inv[qi];

    const int wid = tid >> 6;
    if (wid < 4) {
      f32x4 pacc = {0.f,0.f,0.f,0.f};
#pragma unroll
      for (int kb2 = 0; kb2 < 8; ++kb2) {
        const bf16x8 af  = *reinterpret_cast<const bf16x8*>(&aLb[kb2][l][0]);
        const bf16x8 bff = *reinterpret_cast<const bf16x8*>(&VF[((kb2*4 + wid)*64 + l)*8]);
        pacc = __builtin_amdgcn_mfma_f32_16x16x32_bf16(af, bff, pacc, 0, 0, 0);
      }
      const int b_ = bh >> 3, hh = bh & 7;
      const int colv = hh*DHEAD + wid*16 + (l & 15);
#pragma unroll
      for (int r = 0; r < 4; ++r) {
        const int row = (l >> 4)*4 + r;
        const float stot = reds[row>>2][0][row&3] + reds[row>>2][1][row&3]
                         + reds[row>>2][2][row&3] + reds[row>>2][3][row&3];
        xb[(b_*NL + qt*16 + row)*HIDN + colv] = f2bf(pacc[r] * __builtin_amdgcn_rcpf(stot));
      }
    }
  }
}

// ---------------- mfma_out: out = X(bf16) @ Wo(f32, cvt in-reg)^T + bo --------------
__global__ __launch_bounds__(256) void mfma_out(
    const short* __restrict__ Xb, const float* __restrict__ Wo,
    const float* __restrict__ bo, float* __restrict__ out)
{
  const int wid  = threadIdx.x >> 6;
  const int lane = threadIdx.x & 63;
  const int mt = blockIdx.y * 4 + wid;     // 0..63
  const int nb = blockIdx.x * 32;          // 0..480
  const short* aptr = Xb + (mt*16 + (lane & 15))*HIDN + (lane >> 4)*8;
  const float* wptr = Wo + (nb + (lane & 15))*HIDN + (lane >> 4)*8;

  f32x4 acc[2] = {{0,0,0,0},{0,0,0,0}};
#pragma unroll 4
  for (int k0 = 0; k0 < HIDN; k0 += 32) {
    const bf16x8 af = *reinterpret_cast<const bf16x8*>(aptr + k0);
#pragma unroll
    for (int t = 0; t < 2; ++t) {
      const bf16x8 bf = cvt8(wptr + t*16*HIDN + k0);
      acc[t] = __builtin_amdgcn_mfma_f32_16x16x32_bf16(af, bf, acc[t], 0, 0, 0);
    }
  }

  const int rbase = mt*16 + (lane >> 4)*4;
#pragma unroll
  for (int t = 0; t < 2; ++t) {
    const int c = nb + t*16 + (lane & 15);
    const float bc = bo[c];
#pragma unroll
    for (int r = 0; r < 4; ++r)
      out[(rbase + r)*HIDN + c] = acc[t][r] + bc;
  }
}

extern "C" void kernel_launch(void* const* d_in, const int* in_sizes, int n_in,
                              void* d_out, int out_size, void* d_ws, size_t ws_size,
                              hipStream_t stream) {
  const float* q    = (const float*)d_in[0];
  const float* kin  = (const float*)d_in[1];
  const float* v    = (const float*)d_in[2];
  const float* Wq   = (const float*)d_in[3];
  const float* bq   = (const float*)d_in[4];
  const float* Wk   = (const float*)d_in[5];
  const float* bk   = (const float*)d_in[6];
  const float* Wv   = (const float*)d_in[7];
  const float* bv   = (const float*)d_in[8];
  const float* W1   = (const float*)d_in[9];
  const float* b1   = (const float*)d_in[10];
  const float* W2   = (const float*)d_in[11];
  const float* b2   = (const float*)d_in[12];
  const float* va_w = (const float*)d_in[13];
  const float* Wo   = (const float*)d_in[15];
  const float* bo   = (const float*)d_in[16];

  float* out = (float*)d_out;
  float* ws  = (float*)d_ws;
  float* attn = out + NROW*HIDN;   // output 1: attention [B,H,Lq,Lk]

  proj2<<<dim3(64, 8, 3), 256, 0, stream>>>(q, kin, v, Wq, bq, Wk, bk, Wv, bv,
                                            W1, b1, W2, b2, ws);
  attn_kernel<<<dim3(16, 32), 1024, 0, stream>>>(
      ws + WS_EQ, ws + WS_EK, (const short*)(ws + WS_VF), va_w,
      attn, (short*)(ws + WS_X));
  mfma_out<<<dim3(16, 16), 256, 0, stream>>>(
      (const short*)(ws + WS_X), Wo, bo, out);
}